// Round 1
// 1244.306 us; speedup vs baseline: 1.0577x; 1.0577x over previous
//
#include <hip/hip_runtime.h>
#include <hip/hip_bf16.h>
#include <cstddef>
#include <cstdint>

typedef __hip_bfloat16 bf16;
typedef float floatx4 __attribute__((ext_vector_type(4)));
typedef short shortx8 __attribute__((ext_vector_type(8)));

#define NROWS 8192
#define INDIM 1024
#define OUTDIM 8192
#define CM1 8191

// ---------------------------------------------------------------------------
// async global -> LDS, 16B per lane. LDS dest must be wave-uniform base;
// hardware writes lane l's 16B at base + l*16. Global address is per-lane.
// ---------------------------------------------------------------------------
__device__ __forceinline__ void gload16(const void* g, void* l) {
  __builtin_amdgcn_global_load_lds(
      (const __attribute__((address_space(1))) void*)g,
      (__attribute__((address_space(3))) void*)l, 16, 0, 0);
}

// ---------------------------------------------------------------------------
// Segment accumulation: sums[label[i]] += x[i], cnts[label[i]] += 1
// ---------------------------------------------------------------------------
__global__ __launch_bounds__(256) void seg_acc_kernel(
    const float* __restrict__ x, const int* __restrict__ labels,
    float* __restrict__ sums, int* __restrict__ cnts) {
  int i = blockIdx.x;
  int l = labels[i];
  const float* xr = x + (size_t)i * INDIM;
  float* sr = sums + (size_t)l * INDIM;
  for (int d = threadIdx.x; d < INDIM; d += 256) atomicAdd(&sr[d], xr[d]);
  if (threadIdx.x == 0) atomicAdd(&cnts[l], 1);
}

// ---------------------------------------------------------------------------
// f32 -> bf16 conversion, 8 elements/thread (n_in, n_out multiples of 8;
// elements in [n_in, n_out) are zero-padded)
// ---------------------------------------------------------------------------
__global__ __launch_bounds__(256) void cvt8_kernel(
    const float* __restrict__ in, bf16* __restrict__ out, long n_in, long n_out) {
  long i = ((long)blockIdx.x * 256 + threadIdx.x) * 8;
  if (i >= n_out) return;
  shortx8 o;
  if (i + 8 <= n_in) {
    floatx4 a = *(const floatx4*)(in + i);
    floatx4 b = *(const floatx4*)(in + i + 4);
#pragma unroll
    for (int j = 0; j < 4; j++) {
      o[j] = __builtin_bit_cast(short, __float2bfloat16(a[j]));
      o[j + 4] = __builtin_bit_cast(short, __float2bfloat16(b[j]));
    }
  } else {
#pragma unroll
    for (int j = 0; j < 8; j++) o[j] = 0;
  }
  *(shortx8*)(out + i) = o;
}

// ---------------------------------------------------------------------------
// Build v^T [INDIM][OUTDIM] bf16 via 64x64 LDS transpose tiles.
// Column c in [0,CM1) = class c+1; col CM1 = 0.
// v[c] = new_hist[c] * (1-MU)/(1-MU^clamped)
// Grid: 128 c-tiles * 16 d-tiles = 2048 blocks.
// ---------------------------------------------------------------------------
__global__ __launch_bounds__(256) void make_vt_kernel(
    const float* __restrict__ sums, const int* __restrict__ cnts,
    const float* __restrict__ hist, const int* __restrict__ hist_cnt,
    bf16* __restrict__ vT) {
  __shared__ float tile[64][65];
  __shared__ float scl[64];
  __shared__ float rc[64];
  __shared__ int prs[64];
  const int t = threadIdx.x;
  const int cb = blockIdx.x & 127;
  const int db = blockIdx.x >> 7;
  const int c0 = cb * 64, d0 = db * 64;

  if (t < 64) {
    int c = c0 + t;
    float scale = 0.f, rcnt = 0.f;
    int present = 0;
    if (c < CM1) {
      int cnt = cnts[c + 1];
      present = cnt > 0;
      rcnt = 1.0f / fmaxf((float)cnt, 1.0f);
      int nc = hist_cnt[c] + (present ? 1 : 0);
      float clamped = (float)(nc > 1 ? nc : 1);
      scale = 0.1f / (1.0f - powf(0.9f, clamped));
    }
    scl[t] = scale;
    rc[t] = rcnt;
    prs[t] = present;
  }
  __syncthreads();

  const int dl = t & 63;
  const int cl0 = t >> 6;
#pragma unroll
  for (int ii = 0; ii < 16; ii++) {
    int clc = cl0 * 16 + ii;
    int c = c0 + clc;
    float val = 0.f;
    if (c < CM1) {
      float mean = sums[(size_t)(c + 1) * INDIM + d0 + dl] * rc[clc];
      float h = hist[(size_t)c * INDIM + d0 + dl];
      float nh = prs[clc] ? (0.9f * h + mean) : h;
      val = nh * scl[clc];
    }
    tile[clc][dl] = val;
  }
  __syncthreads();

  const int clw = t & 63;
  const int dl0 = t >> 6;
#pragma unroll
  for (int jj = 0; jj < 16; jj++) {
    int dlc = dl0 * 16 + jj;
    vT[(size_t)(d0 + dlc) * OUTDIM + c0 + clw] = __float2bfloat16(tile[clw][dlc]);
  }
}

// ---------------------------------------------------------------------------
// GEMM: C[m][n] = sum_k A[m][k] * B[n][k]   (A row-major [M][K], B row-major [N][K])
// m97 structure: 128x128 tile, BK=64, linear LDS staged via global_load_lds
// (width 16), chunk-XOR swizzle (inverse-swizzled global source + swizzled
// ds_read), 256 threads (4 waves, 2x2 of 64x64), bijective XCD block swizzle.
// ---------------------------------------------------------------------------
__device__ __forceinline__ void store_c(float* p, float v) { *p = v; }
__device__ __forceinline__ void store_c(bf16* p, float v) { *p = __float2bfloat16(v); }

template <typename OutT>
__global__ __launch_bounds__(256) void gemm_bt_kernel(
    const bf16* __restrict__ A, const bf16* __restrict__ B, OutT* __restrict__ C,
    int K, int ldc) {
  __shared__ bf16 As[128 * 64];
  __shared__ bf16 Bs[128 * 64];
  const int t = threadIdx.x;
  const int lane = t & 63;
  const int wave = t >> 6;

  // XCD-aware bijective swizzle (all grids launched are multiples of 8 blocks)
  const int nwg = gridDim.x * gridDim.y;
  const int orig = blockIdx.y * gridDim.x + blockIdx.x;
  const int wg = (orig & 7) * (nwg >> 3) + (orig >> 3);
  const int bm = (wg / gridDim.x) * 128;
  const int bn = (wg % gridDim.x) * 128;

  const int wm = (wave >> 1) * 64;
  const int wn = (wave & 1) * 64;
  const int r = lane & 15;
  const int q = lane >> 4;
  const int wbase = t & 192;  // wave*64, wave-uniform chunk base

  floatx4 acc[4][4];
#pragma unroll
  for (int i = 0; i < 4; i++)
#pragma unroll
    for (int j = 0; j < 4; j++) acc[i][j] = (floatx4){0.f, 0.f, 0.f, 0.f};

  for (int k0 = 0; k0 < K; k0 += 64) {
    // stage 128x64 A-tile + B-tile: 1024 chunks of 16B each, 4+4 issues/thread.
    // LDS is linear in chunk order (forced by global_load_lds); the global
    // column is inverse-swizzled so that reads can apply the same XOR.
#pragma unroll
    for (int i = 0; i < 4; i++) {
      int c = i * 256 + t;
      int row = c >> 3;
      int gc = ((c & 7) ^ (row & 7)) << 3;  // swizzled logical col (bf16 units)
      gload16(A + (size_t)(bm + row) * K + k0 + gc, &As[(i * 256 + wbase) * 8]);
      gload16(B + (size_t)(bn + row) * K + k0 + gc, &Bs[(i * 256 + wbase) * 8]);
    }
    __syncthreads();  // compiler drains vmcnt(0) before s_barrier
#pragma unroll
    for (int kk = 0; kk < 64; kk += 32) {
      shortx8 af[4], bfr[4];
      const int pc = ((kk >> 3) + q) ^ (r & 7);  // swizzled physical chunk
#pragma unroll
      for (int i = 0; i < 4; i++) {
        af[i] = *(const shortx8*)(&As[(wm + i * 16 + r) * 64 + pc * 8]);
        bfr[i] = *(const shortx8*)(&Bs[(wn + i * 16 + r) * 64 + pc * 8]);
      }
#pragma unroll
      for (int i = 0; i < 4; i++)
#pragma unroll
        for (int j = 0; j < 4; j++)
          acc[i][j] = __builtin_amdgcn_mfma_f32_16x16x32_bf16(af[i], bfr[j], acc[i][j], 0, 0, 0);
    }
    __syncthreads();  // all waves done reading before next stage overwrites
  }

  // C/D layout: n = lane&15, m = (lane>>4)*4 + reg
#pragma unroll
  for (int i = 0; i < 4; i++)
#pragma unroll
    for (int j = 0; j < 4; j++)
#pragma unroll
      for (int rr = 0; rr < 4; rr++) {
        int m = bm + wm + i * 16 + q * 4 + rr;
        int n = bn + wn + j * 16 + r;
        store_c(&C[(size_t)m * ldc + n], acc[i][j][rr]);
      }
}

// ---------------------------------------------------------------------------
// Row softmax over first CM1 cols of wl (bf16, ld=OUTDIM), add bias; col CM1 -> 0
// ---------------------------------------------------------------------------
__global__ __launch_bounds__(256) void softmax_rows_kernel(
    bf16* __restrict__ wl, const float* __restrict__ bias) {
  __shared__ float red[4];
  const int t = threadIdx.x;
  bf16* p = wl + (size_t)blockIdx.x * OUTDIM;
  float vals[32];
  float mx = -1e30f;
#pragma unroll
  for (int i = 0; i < 32; i++) {
    int col = i * 256 + t;
    float v = -1e30f;
    if (col < CM1) v = __bfloat162float(p[col]) + bias[col];
    vals[i] = v;
    mx = fmaxf(mx, v);
  }
  for (int o = 32; o; o >>= 1) mx = fmaxf(mx, __shfl_down(mx, o, 64));
  if ((t & 63) == 0) red[t >> 6] = mx;
  __syncthreads();
  mx = fmaxf(fmaxf(red[0], red[1]), fmaxf(red[2], red[3]));
  __syncthreads();
  float s = 0.f;
#pragma unroll
  for (int i = 0; i < 32; i++) {
    int col = i * 256 + t;
    float e = (col < CM1) ? __expf(vals[i] - mx) : 0.f;
    vals[i] = e;
    s += e;
  }
  for (int o = 32; o; o >>= 1) s += __shfl_down(s, o, 64);
  if ((t & 63) == 0) red[t >> 6] = s;
  __syncthreads();
  s = red[0] + red[1] + red[2] + red[3];
  float rs = 1.0f / s;
#pragma unroll
  for (int i = 0; i < 32; i++) {
    int col = i * 256 + t;
    p[col] = __float2bfloat16(vals[i] * rs);
  }
}

// ---------------------------------------------------------------------------
// g = sigmoid(x . wg + b); feat = bf16(g*x + (1-g)*sub)
// ---------------------------------------------------------------------------
__global__ __launch_bounds__(256) void g_feat_kernel(
    const float* __restrict__ x, const float* __restrict__ wg,
    const float* __restrict__ wgb, const bf16* __restrict__ sub,
    bf16* __restrict__ feat) {
  __shared__ float red[4];
  const int t = threadIdx.x;
  const float* xr = x + (size_t)blockIdx.x * INDIM;
  float dot = 0.f;
#pragma unroll
  for (int i = 0; i < 4; i++) {
    int d = i * 256 + t;
    dot += xr[d] * wg[d];
  }
  for (int o = 32; o; o >>= 1) dot += __shfl_down(dot, o, 64);
  if ((t & 63) == 0) red[t >> 6] = dot;
  __syncthreads();
  dot = red[0] + red[1] + red[2] + red[3];
  float g = 1.0f / (1.0f + __expf(-(dot + wgb[0])));
  const bf16* sr = sub + (size_t)blockIdx.x * INDIM;
  bf16* fr = feat + (size_t)blockIdx.x * INDIM;
#pragma unroll
  for (int i = 0; i < 4; i++) {
    int d = i * 256 + t;
    float f = g * xr[d] + (1.0f - g) * __bfloat162float(sr[d]);
    fr[d] = __float2bfloat16(f);
  }
}

// ---------------------------------------------------------------------------
// Cross-entropy accumulation over rows
// ---------------------------------------------------------------------------
__global__ __launch_bounds__(256) void ce_kernel(
    const float* __restrict__ logits, const int* __restrict__ labels,
    float* __restrict__ acc) {
  __shared__ float red[4];
  const int t = threadIdx.x;
  const float* p = logits + (size_t)blockIdx.x * OUTDIM;
  float vals[32];
  float mx = -1e30f;
#pragma unroll
  for (int i = 0; i < 32; i++) {
    float v = p[i * 256 + t];
    vals[i] = v;
    mx = fmaxf(mx, v);
  }
  for (int o = 32; o; o >>= 1) mx = fmaxf(mx, __shfl_down(mx, o, 64));
  if ((t & 63) == 0) red[t >> 6] = mx;
  __syncthreads();
  mx = fmaxf(fmaxf(red[0], red[1]), fmaxf(red[2], red[3]));
  __syncthreads();
  float s = 0.f;
#pragma unroll
  for (int i = 0; i < 32; i++) s += __expf(vals[i] - mx);
  for (int o = 32; o; o >>= 1) s += __shfl_down(s, o, 64);
  if ((t & 63) == 0) red[t >> 6] = s;
  __syncthreads();
  if (t == 0) {
    s = red[0] + red[1] + red[2] + red[3];
    int l = labels[blockIdx.x];
    if (l >= 0) {
      float nll = mx + logf(s) - p[l];
      atomicAdd(&acc[0], nll);
      atomicAdd(&acc[1], 1.0f);
    }
  }
}

__global__ void finalize_kernel(const float* __restrict__ acc, float* __restrict__ out) {
  out[0] = acc[0] / fmaxf(acc[1], 1.0f);
}

// ---------------------------------------------------------------------------
extern "C" void kernel_launch(void* const* d_in, const int* in_sizes, int n_in,
                              void* d_out, int out_size, void* d_ws, size_t ws_size,
                              hipStream_t stream) {
  const float* x        = (const float*)d_in[0];
  const float* x_ctx    = (const float*)d_in[1];
  const int*   labels   = (const int*)d_in[2];
  const float* cls      = (const float*)d_in[3];
  const float* ctxq_w   = (const float*)d_in[4];
  const float* ctxq_b   = (const float*)d_in[5];
  const float* wg_w     = (const float*)d_in[6];
  const float* wg_b     = (const float*)d_in[7];
  const float* hist     = (const float*)d_in[8];
  const int*   hist_cnt = (const int*)d_in[9];
  float* out = (float*)d_out;

  char* ws = (char*)d_ws;
  float* sums   = (float*)(ws + 0);            // 8192*1024*4 = 33554432
  int*   cnts   = (int*)  (ws + 33554432);     // 32768
  float* acc    = (float*)(ws + 33587200);     // 256
  bf16* xctx_bf = (bf16*) (ws + 33587456);     // 16777216
  bf16* wq_bf   = (bf16*) (ws + 50364672);     // 16777216 (padded row 8191 = 0)
  bf16* cls_bf  = (bf16*) (ws + 67141888);     // 16777216
  bf16* vT      = (bf16*) (ws + 83919104);     // 16777216 [1024][8192]
  bf16* wl      = (bf16*) (ws + 100696320);    // 134217728 [8192][8192]
  bf16* sub_bf  = (bf16*) (ws + 234914048);    // 16777216
  bf16* feat_bf = (bf16*) (ws + 251691264);    // 16777216
  // total: 268468480 bytes

  // zero sums + cnts + acc
  hipMemsetAsync(ws, 0, 33587456 + 256, stream);

  seg_acc_kernel<<<NROWS, 256, 0, stream>>>(x, labels, sums, cnts);
  cvt8_kernel<<<4096, 256, 0, stream>>>(x_ctx, xctx_bf, (long)NROWS * INDIM,
                                        (long)NROWS * INDIM);
  cvt8_kernel<<<4096, 256, 0, stream>>>(ctxq_w, wq_bf, (long)CM1 * INDIM,
                                        (long)OUTDIM * INDIM);
  cvt8_kernel<<<4096, 256, 0, stream>>>(cls, cls_bf, (long)OUTDIM * INDIM,
                                        (long)OUTDIM * INDIM);
  make_vt_kernel<<<2048, 256, 0, stream>>>(sums, cnts, hist, hist_cnt, vT);

  // GEMM1: w_logits = x_ctx @ ctx_q_w^T  [8192 x 8192], K=1024
  gemm_bt_kernel<bf16><<<dim3(64, 64), 256, 0, stream>>>(xctx_bf, wq_bf, wl, 1024, OUTDIM);
  softmax_rows_kernel<<<NROWS, 256, 0, stream>>>(wl, ctxq_b);
  // GEMM2: substitute = w @ v  == w [8192 x 8192(K)] . vT [1024 x 8192(K)]^T
  gemm_bt_kernel<bf16><<<dim3(8, 64), 256, 0, stream>>>(wl, vT, sub_bf, OUTDIM, INDIM);
  g_feat_kernel<<<NROWS, 256, 0, stream>>>(x, wg_w, wg_b, sub_bf, feat_bf);
  // GEMM3: logits = feat @ classifier^T  [8192 x 8192], K=1024 -> d_out+1 (fp32)
  gemm_bt_kernel<float><<<dim3(64, 64), 256, 0, stream>>>(feat_bf, cls_bf, out + 1, 1024, OUTDIM);
  ce_kernel<<<NROWS, 256, 0, stream>>>(out + 1, labels, acc);
  finalize_kernel<<<1, 1, 0, stream>>>(acc, out);
}

// Round 3
// 1184.701 us; speedup vs baseline: 1.1110x; 1.0503x over previous
//
#include <hip/hip_runtime.h>
#include <hip/hip_bf16.h>
#include <cstddef>
#include <cstdint>

typedef __hip_bfloat16 bf16;
typedef float floatx4 __attribute__((ext_vector_type(4)));
typedef short shortx8 __attribute__((ext_vector_type(8)));

#define NROWS 8192
#define INDIM 1024
#define OUTDIM 8192
#define CM1 8191

// ---------------------------------------------------------------------------
// async global -> LDS, 16B per lane. LDS dest must be wave-uniform base;
// hardware writes lane l's 16B at base + l*16. Global address is per-lane.
// ---------------------------------------------------------------------------
__device__ __forceinline__ void gload16(const void* g, void* l) {
  __builtin_amdgcn_global_load_lds(
      (const __attribute__((address_space(1))) void*)g,
      (__attribute__((address_space(3))) void*)l, 16, 0, 0);
}

// ---------------------------------------------------------------------------
// Segment accumulation: sums[label[i]] += x[i], cnts[label[i]] += 1
// ---------------------------------------------------------------------------
__global__ __launch_bounds__(256) void seg_acc_kernel(
    const float* __restrict__ x, const int* __restrict__ labels,
    float* __restrict__ sums, int* __restrict__ cnts) {
  int i = blockIdx.x;
  int l = labels[i];
  const float* xr = x + (size_t)i * INDIM;
  float* sr = sums + (size_t)l * INDIM;
  for (int d = threadIdx.x; d < INDIM; d += 256) atomicAdd(&sr[d], xr[d]);
  if (threadIdx.x == 0) atomicAdd(&cnts[l], 1);
}

// ---------------------------------------------------------------------------
// f32 -> bf16 conversion, 8 elements/thread (n_in, n_out multiples of 8;
// elements in [n_in, n_out) are zero-padded)
// ---------------------------------------------------------------------------
__global__ __launch_bounds__(256) void cvt8_kernel(
    const float* __restrict__ in, bf16* __restrict__ out, long n_in, long n_out) {
  long i = ((long)blockIdx.x * 256 + threadIdx.x) * 8;
  if (i >= n_out) return;
  shortx8 o;
  if (i + 8 <= n_in) {
    floatx4 a = *(const floatx4*)(in + i);
    floatx4 b = *(const floatx4*)(in + i + 4);
#pragma unroll
    for (int j = 0; j < 4; j++) {
      o[j] = __builtin_bit_cast(short, __float2bfloat16(a[j]));
      o[j + 4] = __builtin_bit_cast(short, __float2bfloat16(b[j]));
    }
  } else {
#pragma unroll
    for (int j = 0; j < 8; j++) o[j] = 0;
  }
  *(shortx8*)(out + i) = o;
}

// ---------------------------------------------------------------------------
// Build v^T [INDIM][OUTDIM] bf16 via 64x64 LDS transpose tiles.
// Column c in [0,CM1) = class c+1; col CM1 = 0.
// v[c] = new_hist[c] * (1-MU)/(1-MU^clamped)
// Grid: 128 c-tiles * 16 d-tiles = 2048 blocks.
// ---------------------------------------------------------------------------
__global__ __launch_bounds__(256) void make_vt_kernel(
    const float* __restrict__ sums, const int* __restrict__ cnts,
    const float* __restrict__ hist, const int* __restrict__ hist_cnt,
    bf16* __restrict__ vT) {
  __shared__ float tile[64][65];
  __shared__ float scl[64];
  __shared__ float rc[64];
  __shared__ int prs[64];
  const int t = threadIdx.x;
  const int cb = blockIdx.x & 127;
  const int db = blockIdx.x >> 7;
  const int c0 = cb * 64, d0 = db * 64;

  if (t < 64) {
    int c = c0 + t;
    float scale = 0.f, rcnt = 0.f;
    int present = 0;
    if (c < CM1) {
      int cnt = cnts[c + 1];
      present = cnt > 0;
      rcnt = 1.0f / fmaxf((float)cnt, 1.0f);
      int nc = hist_cnt[c] + (present ? 1 : 0);
      float clamped = (float)(nc > 1 ? nc : 1);
      scale = 0.1f / (1.0f - powf(0.9f, clamped));
    }
    scl[t] = scale;
    rc[t] = rcnt;
    prs[t] = present;
  }
  __syncthreads();

  const int dl = t & 63;
  const int cl0 = t >> 6;
#pragma unroll
  for (int ii = 0; ii < 16; ii++) {
    int clc = cl0 * 16 + ii;
    int c = c0 + clc;
    float val = 0.f;
    if (c < CM1) {
      float mean = sums[(size_t)(c + 1) * INDIM + d0 + dl] * rc[clc];
      float h = hist[(size_t)c * INDIM + d0 + dl];
      float nh = prs[clc] ? (0.9f * h + mean) : h;
      val = nh * scl[clc];
    }
    tile[clc][dl] = val;
  }
  __syncthreads();

  const int clw = t & 63;
  const int dl0 = t >> 6;
#pragma unroll
  for (int jj = 0; jj < 16; jj++) {
    int dlc = dl0 * 16 + jj;
    vT[(size_t)(d0 + dlc) * OUTDIM + c0 + clw] = __float2bfloat16(tile[clw][dlc]);
  }
}

// ---------------------------------------------------------------------------
// GEMM: C[m][n] = sum_k A[m][k] * B[n][k]   (A row-major [M][K], B row-major [N][K])
// m97 structure: 128x128 tile, BK=64, linear LDS staged via global_load_lds
// (width 16), chunk-XOR swizzle (inverse-swizzled global source + swizzled
// ds_read), 256 threads (4 waves, 2x2 of 64x64).
// Default block order: consecutive blocks (same m-row) round-robin across
// XCDs -> each XCD holds only every-8th n-panel of B in L2 (2 MB, resident).
// Measured r0: FETCH=136MB. Chunked XCD swizzle thrashed L2 (r1: 532MB) - no.
// ---------------------------------------------------------------------------
__device__ __forceinline__ void store_c(float* p, float v) { *p = v; }
__device__ __forceinline__ void store_c(bf16* p, float v) { *p = __float2bfloat16(v); }

template <typename OutT>
__global__ __launch_bounds__(256) void gemm_bt_kernel(
    const bf16* __restrict__ A, const bf16* __restrict__ B, OutT* __restrict__ C,
    int K, int ldc) {
  __shared__ bf16 As[128 * 64];
  __shared__ bf16 Bs[128 * 64];
  const int t = threadIdx.x;
  const int lane = t & 63;
  const int wave = t >> 6;

  const int bm = blockIdx.y * 128;
  const int bn = blockIdx.x * 128;

  const int wm = (wave >> 1) * 64;
  const int wn = (wave & 1) * 64;
  const int r = lane & 15;
  const int q = lane >> 4;
  const int wbase = t & 192;  // wave*64, wave-uniform chunk base

  floatx4 acc[4][4];
#pragma unroll
  for (int i = 0; i < 4; i++)
#pragma unroll
    for (int j = 0; j < 4; j++) acc[i][j] = (floatx4){0.f, 0.f, 0.f, 0.f};

  for (int k0 = 0; k0 < K; k0 += 64) {
    // stage 128x64 A-tile + B-tile: 1024 chunks of 16B each, 4+4 issues/thread.
    // LDS is linear in chunk order (forced by global_load_lds); the global
    // column is inverse-swizzled so that reads can apply the same XOR.
#pragma unroll
    for (int i = 0; i < 4; i++) {
      int c = i * 256 + t;
      int row = c >> 3;
      int gc = ((c & 7) ^ (row & 7)) << 3;  // swizzled logical col (bf16 units)
      gload16(A + (size_t)(bm + row) * K + k0 + gc, &As[(i * 256 + wbase) * 8]);
      gload16(B + (size_t)(bn + row) * K + k0 + gc, &Bs[(i * 256 + wbase) * 8]);
    }
    __syncthreads();  // compiler drains vmcnt(0) before s_barrier
#pragma unroll
    for (int kk = 0; kk < 64; kk += 32) {
      shortx8 af[4], bfr[4];
      const int pc = ((kk >> 3) + q) ^ (r & 7);  // swizzled physical chunk
#pragma unroll
      for (int i = 0; i < 4; i++) {
        af[i] = *(const shortx8*)(&As[(wm + i * 16 + r) * 64 + pc * 8]);
        bfr[i] = *(const shortx8*)(&Bs[(wn + i * 16 + r) * 64 + pc * 8]);
      }
#pragma unroll
      for (int i = 0; i < 4; i++)
#pragma unroll
        for (int j = 0; j < 4; j++)
          acc[i][j] = __builtin_amdgcn_mfma_f32_16x16x32_bf16(af[i], bfr[j], acc[i][j], 0, 0, 0);
    }
    __syncthreads();  // all waves done reading before next stage overwrites
  }

  // C/D layout: n = lane&15, m = (lane>>4)*4 + reg
#pragma unroll
  for (int i = 0; i < 4; i++)
#pragma unroll
    for (int j = 0; j < 4; j++)
#pragma unroll
      for (int rr = 0; rr < 4; rr++) {
        int m = bm + wm + i * 16 + q * 4 + rr;
        int n = bn + wn + j * 16 + r;
        store_c(&C[(size_t)m * ldc + n], acc[i][j][rr]);
      }
}

// ---------------------------------------------------------------------------
// Row softmax over first CM1 cols of wl (bf16, ld=OUTDIM), add bias; col CM1 -> 0
// ---------------------------------------------------------------------------
__global__ __launch_bounds__(256) void softmax_rows_kernel(
    bf16* __restrict__ wl, const float* __restrict__ bias) {
  __shared__ float red[4];
  const int t = threadIdx.x;
  bf16* p = wl + (size_t)blockIdx.x * OUTDIM;
  float vals[32];
  float mx = -1e30f;
#pragma unroll
  for (int i = 0; i < 32; i++) {
    int col = i * 256 + t;
    float v = -1e30f;
    if (col < CM1) v = __bfloat162float(p[col]) + bias[col];
    vals[i] = v;
    mx = fmaxf(mx, v);
  }
  for (int o = 32; o; o >>= 1) mx = fmaxf(mx, __shfl_down(mx, o, 64));
  if ((t & 63) == 0) red[t >> 6] = mx;
  __syncthreads();
  mx = fmaxf(fmaxf(red[0], red[1]), fmaxf(red[2], red[3]));
  __syncthreads();
  float s = 0.f;
#pragma unroll
  for (int i = 0; i < 32; i++) {
    int col = i * 256 + t;
    float e = (col < CM1) ? __expf(vals[i] - mx) : 0.f;
    vals[i] = e;
    s += e;
  }
  for (int o = 32; o; o >>= 1) s += __shfl_down(s, o, 64);
  if ((t & 63) == 0) red[t >> 6] = s;
  __syncthreads();
  s = red[0] + red[1] + red[2] + red[3];
  float rs = 1.0f / s;
#pragma unroll
  for (int i = 0; i < 32; i++) {
    int col = i * 256 + t;
    p[col] = __float2bfloat16(vals[i] * rs);
  }
}

// ---------------------------------------------------------------------------
// g = sigmoid(x . wg + b); feat = bf16(g*x + (1-g)*sub)
// ---------------------------------------------------------------------------
__global__ __launch_bounds__(256) void g_feat_kernel(
    const float* __restrict__ x, const float* __restrict__ wg,
    const float* __restrict__ wgb, const bf16* __restrict__ sub,
    bf16* __restrict__ feat) {
  __shared__ float red[4];
  const int t = threadIdx.x;
  const float* xr = x + (size_t)blockIdx.x * INDIM;
  float dot = 0.f;
#pragma unroll
  for (int i = 0; i < 4; i++) {
    int d = i * 256 + t;
    dot += xr[d] * wg[d];
  }
  for (int o = 32; o; o >>= 1) dot += __shfl_down(dot, o, 64);
  if ((t & 63) == 0) red[t >> 6] = dot;
  __syncthreads();
  dot = red[0] + red[1] + red[2] + red[3];
  float g = 1.0f / (1.0f + __expf(-(dot + wgb[0])));
  const bf16* sr = sub + (size_t)blockIdx.x * INDIM;
  bf16* fr = feat + (size_t)blockIdx.x * INDIM;
#pragma unroll
  for (int i = 0; i < 4; i++) {
    int d = i * 256 + t;
    float f = g * xr[d] + (1.0f - g) * __bfloat162float(sr[d]);
    fr[d] = __float2bfloat16(f);
  }
}

// ---------------------------------------------------------------------------
// Cross-entropy accumulation over rows
// ---------------------------------------------------------------------------
__global__ __launch_bounds__(256) void ce_kernel(
    const float* __restrict__ logits, const int* __restrict__ labels,
    float* __restrict__ acc) {
  __shared__ float red[4];
  const int t = threadIdx.x;
  const float* p = logits + (size_t)blockIdx.x * OUTDIM;
  float vals[32];
  float mx = -1e30f;
#pragma unroll
  for (int i = 0; i < 32; i++) {
    float v = p[i * 256 + t];
    vals[i] = v;
    mx = fmaxf(mx, v);
  }
  for (int o = 32; o; o >>= 1) mx = fmaxf(mx, __shfl_down(mx, o, 64));
  if ((t & 63) == 0) red[t >> 6] = mx;
  __syncthreads();
  mx = fmaxf(fmaxf(red[0], red[1]), fmaxf(red[2], red[3]));
  __syncthreads();
  float s = 0.f;
#pragma unroll
  for (int i = 0; i < 32; i++) s += __expf(vals[i] - mx);
  for (int o = 32; o; o >>= 1) s += __shfl_down(s, o, 64);
  if ((t & 63) == 0) red[t >> 6] = s;
  __syncthreads();
  if (t == 0) {
    s = red[0] + red[1] + red[2] + red[3];
    int l = labels[blockIdx.x];
    if (l >= 0) {
      float nll = mx + logf(s) - p[l];
      atomicAdd(&acc[0], nll);
      atomicAdd(&acc[1], 1.0f);
    }
  }
}

__global__ void finalize_kernel(const float* __restrict__ acc, float* __restrict__ out) {
  out[0] = acc[0] / fmaxf(acc[1], 1.0f);
}

// ---------------------------------------------------------------------------
extern "C" void kernel_launch(void* const* d_in, const int* in_sizes, int n_in,
                              void* d_out, int out_size, void* d_ws, size_t ws_size,
                              hipStream_t stream) {
  const float* x        = (const float*)d_in[0];
  const float* x_ctx    = (const float*)d_in[1];
  const int*   labels   = (const int*)d_in[2];
  const float* cls      = (const float*)d_in[3];
  const float* ctxq_w   = (const float*)d_in[4];
  const float* ctxq_b   = (const float*)d_in[5];
  const float* wg_w     = (const float*)d_in[6];
  const float* wg_b     = (const float*)d_in[7];
  const float* hist     = (const float*)d_in[8];
  const int*   hist_cnt = (const int*)d_in[9];
  float* out = (float*)d_out;

  char* ws = (char*)d_ws;
  float* sums   = (float*)(ws + 0);            // 8192*1024*4 = 33554432
  int*   cnts   = (int*)  (ws + 33554432);     // 32768
  float* acc    = (float*)(ws + 33587200);     // 256
  bf16* xctx_bf = (bf16*) (ws + 33587456);     // 16777216
  bf16* wq_bf   = (bf16*) (ws + 50364672);     // 16777216 (padded row 8191 = 0)
  bf16* cls_bf  = (bf16*) (ws + 67141888);     // 16777216
  bf16* vT      = (bf16*) (ws + 83919104);     // 16777216 [1024][8192]
  bf16* wl      = (bf16*) (ws + 100696320);    // 134217728 [8192][8192]
  bf16* sub_bf  = (bf16*) (ws + 234914048);    // 16777216
  bf16* feat_bf = (bf16*) (ws + 251691264);    // 16777216
  // total: 268468480 bytes

  // zero sums + cnts + acc
  hipMemsetAsync(ws, 0, 33587456 + 256, stream);

  seg_acc_kernel<<<NROWS, 256, 0, stream>>>(x, labels, sums, cnts);
  cvt8_kernel<<<4096, 256, 0, stream>>>(x_ctx, xctx_bf, (long)NROWS * INDIM,
                                        (long)NROWS * INDIM);
  cvt8_kernel<<<4096, 256, 0, stream>>>(ctxq_w, wq_bf, (long)CM1 * INDIM,
                                        (long)OUTDIM * INDIM);
  cvt8_kernel<<<4096, 256, 0, stream>>>(cls, cls_bf, (long)OUTDIM * INDIM,
                                        (long)OUTDIM * INDIM);
  make_vt_kernel<<<2048, 256, 0, stream>>>(sums, cnts, hist, hist_cnt, vT);

  // GEMM1: w_logits = x_ctx @ ctx_q_w^T  [8192 x 8192], K=1024
  gemm_bt_kernel<bf16><<<dim3(64, 64), 256, 0, stream>>>(xctx_bf, wq_bf, wl, 1024, OUTDIM);
  softmax_rows_kernel<<<NROWS, 256, 0, stream>>>(wl, ctxq_b);
  // GEMM2: substitute = w @ v  == w [8192 x 8192(K)] . vT [1024 x 8192(K)]^T
  gemm_bt_kernel<bf16><<<dim3(8, 64), 256, 0, stream>>>(wl, vT, sub_bf, OUTDIM, INDIM);
  g_feat_kernel<<<NROWS, 256, 0, stream>>>(x, wg_w, wg_b, sub_bf, feat_bf);
  // GEMM3: logits = feat @ classifier^T  [8192 x 8192], K=1024 -> d_out+1 (fp32)
  gemm_bt_kernel<float><<<dim3(64, 64), 256, 0, stream>>>(feat_bf, cls_bf, out + 1, 1024, OUTDIM);
  ce_kernel<<<NROWS, 256, 0, stream>>>(out + 1, labels, acc);
  finalize_kernel<<<1, 1, 0, stream>>>(acc, out);
}

// Round 4
// 1179.629 us; speedup vs baseline: 1.1157x; 1.0043x over previous
//
#include <hip/hip_runtime.h>
#include <hip/hip_bf16.h>
#include <cstddef>
#include <cstdint>

typedef __hip_bfloat16 bf16;
typedef float floatx4 __attribute__((ext_vector_type(4)));
typedef short shortx8 __attribute__((ext_vector_type(8)));

#define NROWS 8192
#define INDIM 1024
#define OUTDIM 8192
#define CM1 8191

// ---------------------------------------------------------------------------
// async global -> LDS, 16B per lane. LDS dest must be wave-uniform base;
// hardware writes lane l's 16B at base + l*16. Global address is per-lane.
// ---------------------------------------------------------------------------
__device__ __forceinline__ void gload16(const void* g, void* l) {
  __builtin_amdgcn_global_load_lds(
      (const __attribute__((address_space(1))) void*)g,
      (__attribute__((address_space(3))) void*)l, 16, 0, 0);
}

// ---------------------------------------------------------------------------
// Segment accumulation: sums[label[i]] += x[i], cnts[label[i]] += 1
// ---------------------------------------------------------------------------
__global__ __launch_bounds__(256) void seg_acc_kernel(
    const float* __restrict__ x, const int* __restrict__ labels,
    float* __restrict__ sums, int* __restrict__ cnts) {
  int i = blockIdx.x;
  int l = labels[i];
  const float* xr = x + (size_t)i * INDIM;
  float* sr = sums + (size_t)l * INDIM;
  for (int d = threadIdx.x; d < INDIM; d += 256) atomicAdd(&sr[d], xr[d]);
  if (threadIdx.x == 0) atomicAdd(&cnts[l], 1);
}

// ---------------------------------------------------------------------------
// f32 -> bf16 conversion, 8 elements/thread (n_in, n_out multiples of 8;
// elements in [n_in, n_out) are zero-padded)
// ---------------------------------------------------------------------------
__global__ __launch_bounds__(256) void cvt8_kernel(
    const float* __restrict__ in, bf16* __restrict__ out, long n_in, long n_out) {
  long i = ((long)blockIdx.x * 256 + threadIdx.x) * 8;
  if (i >= n_out) return;
  shortx8 o;
  if (i + 8 <= n_in) {
    floatx4 a = *(const floatx4*)(in + i);
    floatx4 b = *(const floatx4*)(in + i + 4);
#pragma unroll
    for (int j = 0; j < 4; j++) {
      o[j] = __builtin_bit_cast(short, __float2bfloat16(a[j]));
      o[j + 4] = __builtin_bit_cast(short, __float2bfloat16(b[j]));
    }
  } else {
#pragma unroll
    for (int j = 0; j < 8; j++) o[j] = 0;
  }
  *(shortx8*)(out + i) = o;
}

// ---------------------------------------------------------------------------
// Build v^T [INDIM][OUTDIM] bf16 via 64x64 LDS transpose tiles.
// ---------------------------------------------------------------------------
__global__ __launch_bounds__(256) void make_vt_kernel(
    const float* __restrict__ sums, const int* __restrict__ cnts,
    const float* __restrict__ hist, const int* __restrict__ hist_cnt,
    bf16* __restrict__ vT) {
  __shared__ float tile[64][65];
  __shared__ float scl[64];
  __shared__ float rc[64];
  __shared__ int prs[64];
  const int t = threadIdx.x;
  const int cb = blockIdx.x & 127;
  const int db = blockIdx.x >> 7;
  const int c0 = cb * 64, d0 = db * 64;

  if (t < 64) {
    int c = c0 + t;
    float scale = 0.f, rcnt = 0.f;
    int present = 0;
    if (c < CM1) {
      int cnt = cnts[c + 1];
      present = cnt > 0;
      rcnt = 1.0f / fmaxf((float)cnt, 1.0f);
      int nc = hist_cnt[c] + (present ? 1 : 0);
      float clamped = (float)(nc > 1 ? nc : 1);
      scale = 0.1f / (1.0f - powf(0.9f, clamped));
    }
    scl[t] = scale;
    rc[t] = rcnt;
    prs[t] = present;
  }
  __syncthreads();

  const int dl = t & 63;
  const int cl0 = t >> 6;
#pragma unroll
  for (int ii = 0; ii < 16; ii++) {
    int clc = cl0 * 16 + ii;
    int c = c0 + clc;
    float val = 0.f;
    if (c < CM1) {
      float mean = sums[(size_t)(c + 1) * INDIM + d0 + dl] * rc[clc];
      float h = hist[(size_t)c * INDIM + d0 + dl];
      float nh = prs[clc] ? (0.9f * h + mean) : h;
      val = nh * scl[clc];
    }
    tile[clc][dl] = val;
  }
  __syncthreads();

  const int clw = t & 63;
  const int dl0 = t >> 6;
#pragma unroll
  for (int jj = 0; jj < 16; jj++) {
    int dlc = dl0 * 16 + jj;
    vT[(size_t)(d0 + dlc) * OUTDIM + c0 + clw] = __float2bfloat16(tile[clw][dlc]);
  }
}

// ---------------------------------------------------------------------------
// GEMM 128x128 (kept for GEMM2, N=1024 shape): m97 structure, BK=64,
// global_load_lds staging, chunk-XOR swizzle, 4 waves. Verified r3.
// ---------------------------------------------------------------------------
__device__ __forceinline__ void store_c(float* p, float v) { *p = v; }
__device__ __forceinline__ void store_c(bf16* p, float v) { *p = __float2bfloat16(v); }

template <typename OutT>
__global__ __launch_bounds__(256) void gemm_bt_kernel(
    const bf16* __restrict__ A, const bf16* __restrict__ B, OutT* __restrict__ C,
    int K, int ldc) {
  __shared__ bf16 As[128 * 64];
  __shared__ bf16 Bs[128 * 64];
  const int t = threadIdx.x;
  const int lane = t & 63;
  const int wave = t >> 6;

  const int bm = blockIdx.y * 128;
  const int bn = blockIdx.x * 128;

  const int wm = (wave >> 1) * 64;
  const int wn = (wave & 1) * 64;
  const int r = lane & 15;
  const int q = lane >> 4;
  const int wbase = t & 192;  // wave*64, wave-uniform chunk base

  floatx4 acc[4][4];
#pragma unroll
  for (int i = 0; i < 4; i++)
#pragma unroll
    for (int j = 0; j < 4; j++) acc[i][j] = (floatx4){0.f, 0.f, 0.f, 0.f};

  for (int k0 = 0; k0 < K; k0 += 64) {
#pragma unroll
    for (int i = 0; i < 4; i++) {
      int c = t + i * 256;
      int row = c >> 3;
      int gc = ((c & 7) ^ (row & 7)) << 3;
      gload16(A + (size_t)(bm + row) * K + k0 + gc, &As[(i * 256 + wbase) * 8]);
      gload16(B + (size_t)(bn + row) * K + k0 + gc, &Bs[(i * 256 + wbase) * 8]);
    }
    __syncthreads();
#pragma unroll
    for (int kk = 0; kk < 64; kk += 32) {
      shortx8 af[4], bfr[4];
      const int pc = ((kk >> 3) + q) ^ (r & 7);
#pragma unroll
      for (int i = 0; i < 4; i++) {
        af[i] = *(const shortx8*)(&As[(wm + i * 16 + r) * 64 + pc * 8]);
        bfr[i] = *(const shortx8*)(&Bs[(wn + i * 16 + r) * 64 + pc * 8]);
      }
#pragma unroll
      for (int i = 0; i < 4; i++)
#pragma unroll
        for (int j = 0; j < 4; j++)
          acc[i][j] = __builtin_amdgcn_mfma_f32_16x16x32_bf16(af[i], bfr[j], acc[i][j], 0, 0, 0);
    }
    __syncthreads();
  }

#pragma unroll
  for (int i = 0; i < 4; i++)
#pragma unroll
    for (int j = 0; j < 4; j++)
#pragma unroll
      for (int rr = 0; rr < 4; rr++) {
        int m = bm + wm + i * 16 + q * 4 + rr;
        int n = bn + wn + j * 16 + r;
        store_c(&C[(size_t)m * ldc + n], acc[i][j][rr]);
      }
}

// ---------------------------------------------------------------------------
// GEMM 256x256 tile, BK=64, 8 waves (2Mx4N), double-buffered LDS (128 KiB),
// single barrier per K-step (stage next tile BEFORE compute -> HBM/L2 latency
// hides under MFMA; __syncthreads' vmcnt(0)+lgkmcnt(0) drain closes the step).
// Chunk-XOR LDS swizzle (r1: measured 0 bank conflicts). K multiple of 128.
// bf16 output goes through a per-wave LDS repack -> full-128B-line stores
// (direct 2B stores measured 2.2x write amplification, 278MB vs 128MB).
// ---------------------------------------------------------------------------
template <typename OutT>
__global__ __launch_bounds__(512) void gemm256_kernel(
    const bf16* __restrict__ A, const bf16* __restrict__ B, OutT* __restrict__ C,
    int K, int ldc) {
  __shared__ bf16 As[2][256 * 64];
  __shared__ bf16 Bs[2][256 * 64];
  const int t = threadIdx.x;          // 0..511
  const int lane = t & 63;
  const int wave = t >> 6;            // 0..7
  const int bm = blockIdx.y * 256;
  const int bn = blockIdx.x * 256;
  const int wr = (wave >> 2) * 128;   // 0 / 128
  const int wc = (wave & 3) * 64;     // 0 / 64 / 128 / 192
  const int r = lane & 15;
  const int q = lane >> 4;

  floatx4 acc[8][4];
#pragma unroll
  for (int i = 0; i < 8; i++)
#pragma unroll
    for (int j = 0; j < 4; j++) acc[i][j] = (floatx4){0.f, 0.f, 0.f, 0.f};

  // stage one 256x64 A-tile + B-tile into buffer `sel` (8 gloads/thread)
#define STAGE256(sel, kk0)                                                        \
  {                                                                               \
    _Pragma("unroll") for (int i = 0; i < 4; i++) {                               \
      int c = i * 512 + t;                                                        \
      int row = c >> 3;                                                           \
      int gc = ((c & 7) ^ (row & 7)) << 3;                                        \
      gload16(A + (size_t)(bm + row) * K + (kk0) + gc,                            \
              &As[sel][(i * 512 + wave * 64) * 8]);                               \
      gload16(B + (size_t)(bn + row) * K + (kk0) + gc,                            \
              &Bs[sel][(i * 512 + wave * 64) * 8]);                               \
    }                                                                             \
  }

#define COMPUTE256(sel)                                                           \
  {                                                                               \
    _Pragma("unroll") for (int kk = 0; kk < 64; kk += 32) {                       \
      shortx8 bfr[4];                                                             \
      _Pragma("unroll") for (int j = 0; j < 4; j++) {                             \
        int br = wc + j * 16 + r;                                                 \
        bfr[j] = *(const shortx8*)(&Bs[sel][br * 64 +                             \
                                           ((((kk >> 3) + q) ^ (br & 7)) << 3)]); \
      }                                                                           \
      _Pragma("unroll") for (int i = 0; i < 8; i++) {                             \
        int ar = wr + i * 16 + r;                                                 \
        shortx8 af = *(const shortx8*)(&As[sel][ar * 64 +                         \
                                           ((((kk >> 3) + q) ^ (ar & 7)) << 3)]); \
        _Pragma("unroll") for (int j = 0; j < 4; j++)                             \
          acc[i][j] =                                                             \
              __builtin_amdgcn_mfma_f32_16x16x32_bf16(af, bfr[j], acc[i][j], 0, 0, 0); \
      }                                                                           \
    }                                                                             \
  }

  const int nk = K >> 6;  // K-tiles (16 for K=1024), assumed even
  STAGE256(0, 0);
  __syncthreads();
  for (int kt = 0; kt < nk - 2; kt += 2) {
    STAGE256(1, (kt + 1) * 64);
    COMPUTE256(0);
    __syncthreads();
    STAGE256(0, (kt + 2) * 64);
    COMPUTE256(1);
    __syncthreads();
  }
  STAGE256(1, (nk - 1) * 64);
  COMPUTE256(0);
  __syncthreads();
  COMPUTE256(1);

  if constexpr (sizeof(OutT) == 2) {
    // bf16 epilogue: per-wave 16x64 LDS slab -> coalesced 16B stores
    __syncthreads();  // all waves done reading LDS
    bf16* slab = ((bf16*)As) + wave * 1024;  // 2KB per wave
    const int lr = lane >> 2;        // 0..15
    const int lc = (lane & 3) * 16;  // 0,16,32,48
#pragma unroll
    for (int i = 0; i < 8; i++) {
#pragma unroll
      for (int j = 0; j < 4; j++)
#pragma unroll
        for (int rr = 0; rr < 4; rr++)
          slab[(q * 4 + rr) * 64 + j * 16 + r] = __float2bfloat16(acc[i][j][rr]);
      shortx8 v0 = *(const shortx8*)(&slab[lr * 64 + lc]);
      shortx8 v1 = *(const shortx8*)(&slab[lr * 64 + lc + 8]);
      OutT* crow = C + (size_t)(bm + wr + i * 16 + lr) * ldc + bn + wc + lc;
      *(shortx8*)crow = v0;
      *(shortx8*)(crow + 8) = v1;
    }
  } else {
    // fp32: 16 lanes x 4B = 64B sector-aligned per quarter-wave, no amplification
#pragma unroll
    for (int i = 0; i < 8; i++)
#pragma unroll
      for (int j = 0; j < 4; j++)
#pragma unroll
        for (int rr = 0; rr < 4; rr++) {
          int m = bm + wr + i * 16 + q * 4 + rr;
          int n = bn + wc + j * 16 + r;
          C[(size_t)m * ldc + n] = acc[i][j][rr];
        }
  }
#undef STAGE256
#undef COMPUTE256
}

// ---------------------------------------------------------------------------
// Row softmax over first CM1 cols of wl (bf16, ld=OUTDIM), add bias; col CM1 -> 0
// ---------------------------------------------------------------------------
__global__ __launch_bounds__(256) void softmax_rows_kernel(
    bf16* __restrict__ wl, const float* __restrict__ bias) {
  __shared__ float red[4];
  const int t = threadIdx.x;
  bf16* p = wl + (size_t)blockIdx.x * OUTDIM;
  float vals[32];
  float mx = -1e30f;
#pragma unroll
  for (int i = 0; i < 32; i++) {
    int col = i * 256 + t;
    float v = -1e30f;
    if (col < CM1) v = __bfloat162float(p[col]) + bias[col];
    vals[i] = v;
    mx = fmaxf(mx, v);
  }
  for (int o = 32; o; o >>= 1) mx = fmaxf(mx, __shfl_down(mx, o, 64));
  if ((t & 63) == 0) red[t >> 6] = mx;
  __syncthreads();
  mx = fmaxf(fmaxf(red[0], red[1]), fmaxf(red[2], red[3]));
  __syncthreads();
  float s = 0.f;
#pragma unroll
  for (int i = 0; i < 32; i++) {
    int col = i * 256 + t;
    float e = (col < CM1) ? __expf(vals[i] - mx) : 0.f;
    vals[i] = e;
    s += e;
  }
  for (int o = 32; o; o >>= 1) s += __shfl_down(s, o, 64);
  if ((t & 63) == 0) red[t >> 6] = s;
  __syncthreads();
  s = red[0] + red[1] + red[2] + red[3];
  float rs = 1.0f / s;
#pragma unroll
  for (int i = 0; i < 32; i++) {
    int col = i * 256 + t;
    p[col] = __float2bfloat16(vals[i] * rs);
  }
}

// ---------------------------------------------------------------------------
// g = sigmoid(x . wg + b); feat = bf16(g*x + (1-g)*sub)
// ---------------------------------------------------------------------------
__global__ __launch_bounds__(256) void g_feat_kernel(
    const float* __restrict__ x, const float* __restrict__ wg,
    const float* __restrict__ wgb, const bf16* __restrict__ sub,
    bf16* __restrict__ feat) {
  __shared__ float red[4];
  const int t = threadIdx.x;
  const float* xr = x + (size_t)blockIdx.x * INDIM;
  float dot = 0.f;
#pragma unroll
  for (int i = 0; i < 4; i++) {
    int d = i * 256 + t;
    dot += xr[d] * wg[d];
  }
  for (int o = 32; o; o >>= 1) dot += __shfl_down(dot, o, 64);
  if ((t & 63) == 0) red[t >> 6] = dot;
  __syncthreads();
  dot = red[0] + red[1] + red[2] + red[3];
  float g = 1.0f / (1.0f + __expf(-(dot + wgb[0])));
  const bf16* sr = sub + (size_t)blockIdx.x * INDIM;
  bf16* fr = feat + (size_t)blockIdx.x * INDIM;
#pragma unroll
  for (int i = 0; i < 4; i++) {
    int d = i * 256 + t;
    float f = g * xr[d] + (1.0f - g) * __bfloat162float(sr[d]);
    fr[d] = __float2bfloat16(f);
  }
}

// ---------------------------------------------------------------------------
// Cross-entropy accumulation over rows
// ---------------------------------------------------------------------------
__global__ __launch_bounds__(256) void ce_kernel(
    const float* __restrict__ logits, const int* __restrict__ labels,
    float* __restrict__ acc) {
  __shared__ float red[4];
  const int t = threadIdx.x;
  const float* p = logits + (size_t)blockIdx.x * OUTDIM;
  float vals[32];
  float mx = -1e30f;
#pragma unroll
  for (int i = 0; i < 32; i++) {
    float v = p[i * 256 + t];
    vals[i] = v;
    mx = fmaxf(mx, v);
  }
  for (int o = 32; o; o >>= 1) mx = fmaxf(mx, __shfl_down(mx, o, 64));
  if ((t & 63) == 0) red[t >> 6] = mx;
  __syncthreads();
  mx = fmaxf(fmaxf(red[0], red[1]), fmaxf(red[2], red[3]));
  __syncthreads();
  float s = 0.f;
#pragma unroll
  for (int i = 0; i < 32; i++) s += __expf(vals[i] - mx);
  for (int o = 32; o; o >>= 1) s += __shfl_down(s, o, 64);
  if ((t & 63) == 0) red[t >> 6] = s;
  __syncthreads();
  if (t == 0) {
    s = red[0] + red[1] + red[2] + red[3];
    int l = labels[blockIdx.x];
    if (l >= 0) {
      float nll = mx + logf(s) - p[l];
      atomicAdd(&acc[0], nll);
      atomicAdd(&acc[1], 1.0f);
    }
  }
}

__global__ void finalize_kernel(const float* __restrict__ acc, float* __restrict__ out) {
  out[0] = acc[0] / fmaxf(acc[1], 1.0f);
}

// ---------------------------------------------------------------------------
extern "C" void kernel_launch(void* const* d_in, const int* in_sizes, int n_in,
                              void* d_out, int out_size, void* d_ws, size_t ws_size,
                              hipStream_t stream) {
  const float* x        = (const float*)d_in[0];
  const float* x_ctx    = (const float*)d_in[1];
  const int*   labels   = (const int*)d_in[2];
  const float* cls      = (const float*)d_in[3];
  const float* ctxq_w   = (const float*)d_in[4];
  const float* ctxq_b   = (const float*)d_in[5];
  const float* wg_w     = (const float*)d_in[6];
  const float* wg_b     = (const float*)d_in[7];
  const float* hist     = (const float*)d_in[8];
  const int*   hist_cnt = (const int*)d_in[9];
  float* out = (float*)d_out;

  char* ws = (char*)d_ws;
  float* sums   = (float*)(ws + 0);            // 8192*1024*4 = 33554432
  int*   cnts   = (int*)  (ws + 33554432);     // 32768
  float* acc    = (float*)(ws + 33587200);     // 256
  bf16* xctx_bf = (bf16*) (ws + 33587456);     // 16777216
  bf16* wq_bf   = (bf16*) (ws + 50364672);     // 16777216 (padded row 8191 = 0)
  bf16* cls_bf  = (bf16*) (ws + 67141888);     // 16777216
  bf16* vT      = (bf16*) (ws + 83919104);     // 16777216 [1024][8192]
  bf16* wl      = (bf16*) (ws + 100696320);    // 134217728 [8192][8192]
  bf16* sub_bf  = (bf16*) (ws + 234914048);    // 16777216
  bf16* feat_bf = (bf16*) (ws + 251691264);    // 16777216
  // total: 268468480 bytes

  // zero sums + cnts + acc
  hipMemsetAsync(ws, 0, 33587456 + 256, stream);

  seg_acc_kernel<<<NROWS, 256, 0, stream>>>(x, labels, sums, cnts);
  cvt8_kernel<<<4096, 256, 0, stream>>>(x_ctx, xctx_bf, (long)NROWS * INDIM,
                                        (long)NROWS * INDIM);
  cvt8_kernel<<<4096, 256, 0, stream>>>(ctxq_w, wq_bf, (long)CM1 * INDIM,
                                        (long)OUTDIM * INDIM);
  cvt8_kernel<<<4096, 256, 0, stream>>>(cls, cls_bf, (long)OUTDIM * INDIM,
                                        (long)OUTDIM * INDIM);
  make_vt_kernel<<<2048, 256, 0, stream>>>(sums, cnts, hist, hist_cnt, vT);

  // GEMM1: w_logits = x_ctx @ ctx_q_w^T  [8192 x 8192], K=1024 (256^2 tiles)
  gemm256_kernel<bf16><<<dim3(32, 32), 512, 0, stream>>>(xctx_bf, wq_bf, wl, 1024, OUTDIM);
  softmax_rows_kernel<<<NROWS, 256, 0, stream>>>(wl, ctxq_b);
  // GEMM2: substitute = w @ v  == w [8192 x 8192(K)] . vT [1024 x 8192(K)]^T
  gemm_bt_kernel<bf16><<<dim3(8, 64), 256, 0, stream>>>(wl, vT, sub_bf, OUTDIM, INDIM);
  g_feat_kernel<<<NROWS, 256, 0, stream>>>(x, wg_w, wg_b, sub_bf, feat_bf);
  // GEMM3: logits = feat @ classifier^T  [8192 x 8192], K=1024 -> d_out+1 (fp32)
  gemm256_kernel<float><<<dim3(32, 32), 512, 0, stream>>>(feat_bf, cls_bf, out + 1, 1024, OUTDIM);
  ce_kernel<<<NROWS, 256, 0, stream>>>(out + 1, labels, acc);
  finalize_kernel<<<1, 1, 0, stream>>>(acc, out);
}